// Round 10
// baseline (262.997 us; speedup 1.0000x reference)
//
#include <hip/hip_runtime.h>
#include <hip/hip_bf16.h>

typedef __bf16 bf16;
typedef bf16 bf16x8 __attribute__((ext_vector_type(8)));
typedef bf16 bf16x4 __attribute__((ext_vector_type(4)));
typedef float f32x4 __attribute__((ext_vector_type(4)));

#define SCALE_LOG2 0.06376237f   // (1/sqrt(512)) * log2(e): scores in log2 domain

// ---------------------------------------------------------------------------
// I/O FP32; internal bf16 MFMA. Workspace (bf16 elems):
// qh 2M | kh 2M | vT 2M | phx 4M | ctx 2M | WqT/WpT/WfT 0.25M x3
// ---------------------------------------------------------------------------

// ------------- prep: LDS-tiled transpose fp32 W -> bf16 W^T
__global__ __launch_bounds__(256) void prep_kernel(
    const float* __restrict__ Wq, const float* __restrict__ Wp, const float* __restrict__ Wf,
    bf16* __restrict__ WqT, bf16* __restrict__ WpT, bf16* __restrict__ WfT)
{
  const int tid = threadIdx.x;
  __shared__ bf16 t[64][72];
  const int m = blockIdx.x >> 6;
  const int tb = blockIdx.x & 63;
  const int tr = tb >> 3, tc = tb & 7;
  const float* W = (m == 0) ? Wq : (m == 1) ? Wp : Wf;
  bf16*        O = (m == 0) ? WqT : (m == 1) ? WpT : WfT;
  const int r = tid >> 2, cg = tid & 3;
  {
    const float* src = W + (size_t)(tr * 64 + r) * 512 + tc * 64 + cg * 16;
    f32x4 a = *(const f32x4*)src, b2 = *(const f32x4*)(src + 4);
    f32x4 c = *(const f32x4*)(src + 8), d = *(const f32x4*)(src + 12);
    bf16x8 lo, hi;
#pragma unroll
    for (int j = 0; j < 4; j++) { lo[j] = (bf16)a[j]; lo[4 + j] = (bf16)b2[j]; hi[j] = (bf16)c[j]; hi[4 + j] = (bf16)d[j]; }
    *(bf16x8*)(&t[r][cg * 16])     = lo;
    *(bf16x8*)(&t[r][cg * 16 + 8]) = hi;
  }
  __syncthreads();
  bf16x8 o0, o1;
#pragma unroll
  for (int j = 0; j < 8; j++) { o0[j] = t[cg * 16 + j][r]; o1[j] = t[cg * 16 + 8 + j][r]; }
  bf16* dst = O + (size_t)(tc * 64 + r) * 512 + tr * 64 + cg * 16;
  *(bf16x8*)dst = o0;
  *(bf16x8*)(dst + 8) = o1;
}

// ------------- projection GEMM, BARRIER-FREE wave tiles (no LDS, no syncthreads)
// Wave owns 16 rr x 64 nn. A = W^T rows (nn), B = X rows (rr, fp32->bf16 in regs).
// D layout: lane(quad,ln) reg r -> nn-sub row quad*4+r, rr col ln (b64-friendly stores).
// wg in [0,2048): rr_glob = wg>>1 (kind = rr_glob>>8), nn-tile = (wg&1)*4+wave.
__global__ __launch_bounds__(256, 8) void proj_gemm(
    const float* __restrict__ q, const float* __restrict__ k, const float* __restrict__ v,
    const float* __restrict__ pos,
    const bf16* __restrict__ WqT, const bf16* __restrict__ WpT, const float* __restrict__ bq,
    bf16* __restrict__ qh, bf16* __restrict__ kh, bf16* __restrict__ vT, bf16* __restrict__ phx)
{
  const int tid = threadIdx.x;
  const int wave = tid >> 6, lane = tid & 63, quad = lane >> 4, ln = lane & 15;
  const int wg = blockIdx.x;
  const int rr_glob = wg >> 1;
  const int kind = rr_glob >> 8;            // 0=q 1=k 2=v 3=pos
  const int rr0 = (rr_glob & 255) * 16;
  const int nn0 = ((wg & 1) * 4 + wave) * 64;
  const float* X = (kind == 0) ? q : (kind == 1) ? k : (kind == 2) ? v : pos;
  const bf16* WT = (kind < 3) ? WqT : WpT;

  f32x4 acc[4] = {};   // [i: nn-sub]

  const float* xp = X + (size_t)(rr0 + ln) * 512 + quad * 8;
  const bf16*  wp = WT + (size_t)(nn0 + ln) * 512 + quad * 8;
#pragma unroll 4
  for (int ks = 0; ks < 16; ks++) {
    const int k0 = ks * 32;
    f32x4 lo = *(const f32x4*)(xp + k0);
    f32x4 hi = *(const f32x4*)(xp + k0 + 4);
    bf16x8 xf;
#pragma unroll
    for (int j = 0; j < 4; j++) { xf[j] = (bf16)lo[j]; xf[4 + j] = (bf16)hi[j]; }
#pragma unroll
    for (int i = 0; i < 4; i++) {
      bf16x8 wf = *(const bf16x8*)(wp + (size_t)i * 16 * 512 + k0);
      acc[i] = __builtin_amdgcn_mfma_f32_16x16x32_bf16(wf, xf, acc[i], 0, 0, 0);
    }
  }

  // epilogue: nn = nn0+16i+4quad+r (4-run), rr = rr0+ln
  const int rr = rr0 + ln;
  const int bb = rr >> 10, tt = rr & 1023;
#pragma unroll
  for (int i = 0; i < 4; i++) {
    const int nnb = nn0 + i * 16 + quad * 4;
    const int dd0 = nnb & 31, hh = nnb >> 5;
    const size_t base = (size_t)(bb * 16 + hh);
    f32x4 b4 = {0.f, 0.f, 0.f, 0.f};
    if (kind < 3) b4 = *(const f32x4*)(bq + nnb);
    bf16x4 pk;
#pragma unroll
    for (int r = 0; r < 4; r++) pk[r] = (bf16)(acc[i][r] + b4[r]);
    if (kind == 0)      *(bf16x4*)(qh + (base * 1024 + tt) * 32 + dd0) = pk;
    else if (kind == 1) *(bf16x4*)(kh + (base * 1024 + tt) * 32 + dd0) = pk;
    else if (kind == 2) {
#pragma unroll
      for (int r = 0; r < 4; r++) vT[(base * 32 + dd0 + r) * 1024 + tt] = pk[r];
    } else {
      *(bf16x4*)(phx + (base * 2048 + tt) * 32 + dd0) = pk;
      if (tt <= 1021) *(bf16x4*)(phx + (base * 2048 + tt + 1025) * 32 + dd0) = pk;
      if (tt == 1023) {   // fused zero rows 1024 & 2047 (unique writer per (bb,hh,dd0))
        bf16x4 zz = {};
        *(bf16x4*)(phx + (base * 2048 + 1024) * 32 + dd0) = zz;
        *(bf16x4*)(phx + (base * 2048 + 2047) * 32 + dd0) = zz;
      }
    }
  }
}

// ------------- fused flash attention (r8 version: transposed dataflow, barrier-free,
// log2-domain static softmax — no cross-lane ops in the loop)
__global__ __launch_bounds__(256, 4) void attn_kernel(
    const bf16* __restrict__ qh, const bf16* __restrict__ kh,
    const bf16* __restrict__ vT, const bf16* __restrict__ phx,
    const float* __restrict__ u_bias, const float* __restrict__ v_bias,
    bf16* __restrict__ ctx)
{
  __shared__ float fs[4 * 16 * 84];   // per-wave F band [t=16][j=80 pad 84] 21,504 B
  __shared__ bf16  pb[4 * 16 * 72];   // per-wave P [t=16][s=64 pad 72]       9,216 B

  const int tid = threadIdx.x;
  const int wave = tid >> 6, lane = tid & 63, quad = lane >> 4, ln = lane & 15;
  const int wg = blockIdx.x;
  const int bh = wg & 63, tq = wg >> 6;     // XCD-friendly: same head -> same wg%8
  const int h = bh & 15, b = bh >> 4;
  const int t0 = tq * 64;
  const bf16* qh_h  = qh  + (size_t)bh * 1024 * 32;
  const bf16* kh_h  = kh  + (size_t)bh * 1024 * 32;
  const bf16* vT_h  = vT  + (size_t)bh * 32 * 1024;
  const bf16* phx_h = phx + (size_t)bh * 2048 * 32;

  float* fsw = fs + wave * 16 * 84;
  bf16*  pbw = pb + wave * 16 * 72;

  bf16x8 qu, qva, qvn;
  {
    const int t = t0 + wave * 16 + ln;
    bf16x8 q0 = *(const bf16x8*)(qh_h + (size_t)t * 32 + quad * 8);
    bf16x8 q1 = *(const bf16x8*)(qh_h + (size_t)(t + 1) * 32 + quad * 8);  // t=1023 tail: never used
    const float* ubp = u_bias + h * 32 + quad * 8;
    const float* vbp = v_bias + h * 32 + quad * 8;
#pragma unroll
    for (int j = 0; j < 8; j++) {
      qu[j]  = (bf16)(((float)q0[j] + ubp[j]) * SCALE_LOG2);
      qva[j] = (bf16)(((float)q0[j] + vbp[j]) * SCALE_LOG2);
      qvn[j] = (bf16)(((float)q1[j] + vbp[j]) * SCALE_LOG2);
    }
  }

  f32x4 O0 = {0.f, 0.f, 0.f, 0.f}, O1 = {0.f, 0.f, 0.f, 0.f};
  float l_lane = 0.0f;
  const f32x4 zf = {0.f, 0.f, 0.f, 0.f};

#pragma unroll 2
  for (int si = 0; si < 16; si++) {
    const int s0 = si * 64;
    const int jb0 = s0 - t0 + 960 + (3 - wave) * 16;   // 16-aligned

    // ---- F band: 5 subtiles
#pragma unroll
    for (int i = 0; i < 5; i++) {
      bf16x8 pbf = *(const bf16x8*)(phx_h + (size_t)(jb0 + i * 16 + ln) * 32 + quad * 8);
      bf16x8 bsel = (jb0 + i * 16 >= 1024) ? qvn : qva;
      f32x4 f = __builtin_amdgcn_mfma_f32_16x16x32_bf16(pbf, bsel, zf, 0, 0, 0);
      *(f32x4*)(fsw + ln * 84 + i * 16 + quad * 4) = f;
    }

    // ---- content: S^T
    f32x4 c[4];
#pragma unroll
    for (int cs = 0; cs < 4; cs++) {
      bf16x8 kbf = *(const bf16x8*)(kh_h + (size_t)(s0 + cs * 16 + ln) * 32 + quad * 8);
      c[cs] = __builtin_amdgcn_mfma_f32_16x16x32_bf16(kbf, qu, zf, 0, 0, 0);
    }

    // ---- combine + exp2 + accumulate l + stage P
#pragma unroll
    for (int cs = 0; cs < 4; cs++) {
      bf16x4 pk;
#pragma unroll
      for (int r = 0; r < 4; r++) {
        const int col = cs * 16 + quad * 4 + r - ln + 15;   // [0,78]
        const float p = exp2f(c[cs][r] + fsw[ln * 84 + col]);
        l_lane += p;
        pk[r] = (bf16)p;
      }
      *(bf16x4*)(pbw + ln * 72 + cs * 16 + quad * 4) = pk;
    }

    // ---- PV
#pragma unroll
    for (int kb = 0; kb < 2; kb++) {
      bf16x8 a  = *(const bf16x8*)(pbw + ln * 72 + kb * 32 + quad * 8);
      bf16x8 b0 = *(const bf16x8*)(vT_h + (size_t)ln * 1024 + s0 + kb * 32 + quad * 8);
      bf16x8 b1 = *(const bf16x8*)(vT_h + (size_t)(16 + ln) * 1024 + s0 + kb * 32 + quad * 8);
      O0 = __builtin_amdgcn_mfma_f32_16x16x32_bf16(a, b0, O0, 0, 0, 0);
      O1 = __builtin_amdgcn_mfma_f32_16x16x32_bf16(a, b1, O1, 0, 0, 0);
    }
  }

  l_lane += __shfl_xor(l_lane, 16);
  l_lane += __shfl_xor(l_lane, 32);
#pragma unroll
  for (int r = 0; r < 4; r++) {
    const float lr = __shfl(l_lane, quad * 4 + r);
    const float inv = 1.0f / lr;
    const int t = t0 + wave * 16 + quad * 4 + r;
    const size_t o = ((size_t)(b * 1024 + t)) * 512 + h * 32;
    ctx[o + ln]      = (bf16)(O0[r] * inv);
    ctx[o + 16 + ln] = (bf16)(O1[r] * inv);
  }
}

// ------------- output projection, BARRIER-FREE wave tiles: ctx @ Wf + bf -> out (fp32)
// Wave owns 16 rr x 64 nn; A = WfT rows, B = ctx rows (bf16 b128).
__global__ __launch_bounds__(256, 8) void out_gemm(
    const bf16* __restrict__ ctx, const bf16* __restrict__ WfT, const float* __restrict__ bfv,
    float* __restrict__ out)
{
  const int tid = threadIdx.x;
  const int wave = tid >> 6, lane = tid & 63, quad = lane >> 4, ln = lane & 15;
  const int wg = blockIdx.x;                // [0,512)
  const int rr0 = (wg >> 1) * 16;
  const int nn0 = ((wg & 1) * 4 + wave) * 64;

  f32x4 acc[4] = {};
  const bf16* cp = ctx + (size_t)(rr0 + ln) * 512 + quad * 8;
  const bf16* wp = WfT + (size_t)(nn0 + ln) * 512 + quad * 8;
#pragma unroll 4
  for (int ks = 0; ks < 16; ks++) {
    const int k0 = ks * 32;
    bf16x8 cf = *(const bf16x8*)(cp + k0);
#pragma unroll
    for (int i = 0; i < 4; i++) {
      bf16x8 wf = *(const bf16x8*)(wp + (size_t)i * 16 * 512 + k0);
      acc[i] = __builtin_amdgcn_mfma_f32_16x16x32_bf16(wf, cf, acc[i], 0, 0, 0);
    }
  }

  const int rr = rr0 + ln;
#pragma unroll
  for (int i = 0; i < 4; i++) {
    const int nnb = nn0 + i * 16 + quad * 4;
    f32x4 b4 = *(const f32x4*)(bfv + nnb);
    f32x4 o;
#pragma unroll
    for (int r = 0; r < 4; r++) o[r] = acc[i][r] + b4[r];
    *(f32x4*)(out + (size_t)rr * 512 + nnb) = o;
  }
}

// ---------------------------------------------------------------------------
extern "C" void kernel_launch(void* const* d_in, const int* in_sizes, int n_in,
                              void* d_out, int out_size, void* d_ws, size_t ws_size,
                              hipStream_t stream) {
  const float* q   = (const float*)d_in[0];
  const float* k   = (const float*)d_in[1];
  const float* v   = (const float*)d_in[2];
  const float* pe  = (const float*)d_in[3];
  const float* Wq  = (const float*)d_in[4];
  const float* bq  = (const float*)d_in[5];
  const float* Wp  = (const float*)d_in[6];
  const float* Wf  = (const float*)d_in[7];
  const float* bfv = (const float*)d_in[8];
  const float* ub  = (const float*)d_in[9];
  const float* vb  = (const float*)d_in[10];

  bf16* ws  = (bf16*)d_ws;
  bf16* qh  = ws;                  // qh first: t+1 tail reads land in kh (finite, unused)
  bf16* kh  = qh + 2097152;
  bf16* vT  = kh + 2097152;
  bf16* phx = vT + 2097152;
  bf16* ctx = phx + 4194304;
  bf16* WqT = ctx + 2097152;
  bf16* WpT = WqT + 262144;
  bf16* WfT = WpT + 262144;

  prep_kernel<<<192, 256, 0, stream>>>(Wq, Wp, Wf, WqT, WpT, WfT);
  proj_gemm<<<2048, 256, 0, stream>>>(q, k, v, pe, WqT, WpT, bq, qh, kh, vT, phx);
  attn_kernel<<<1024, 256, 0, stream>>>(qh, kh, vT, phx, ub, vb, ctx);
  out_gemm<<<512, 256, 0, stream>>>(ctx, WfT, bfv, (float*)d_out);
}

// Round 11
// 199.768 us; speedup vs baseline: 1.3165x; 1.3165x over previous
//
#include <hip/hip_runtime.h>
#include <hip/hip_bf16.h>

typedef __bf16 bf16;
typedef bf16 bf16x8 __attribute__((ext_vector_type(8)));
typedef bf16 bf16x4 __attribute__((ext_vector_type(4)));
typedef float f32x4 __attribute__((ext_vector_type(4)));

#define SCALE_LOG2 0.06376237f   // (1/sqrt(512)) * log2(e): scores in log2 domain

// ---------------------------------------------------------------------------
// I/O FP32; internal bf16 MFMA. Workspace (bf16 elems):
// qh 2M | kh 2M | vT 2M | phx 4M | ctx 2M | WqT/WpT/WfT 0.25M x3
// ---------------------------------------------------------------------------

// ------------- prep: LDS-tiled transpose fp32 W -> bf16 W^T
__global__ __launch_bounds__(256) void prep_kernel(
    const float* __restrict__ Wq, const float* __restrict__ Wp, const float* __restrict__ Wf,
    bf16* __restrict__ WqT, bf16* __restrict__ WpT, bf16* __restrict__ WfT)
{
  const int tid = threadIdx.x;
  __shared__ bf16 t[64][72];
  const int m = blockIdx.x >> 6;
  const int tb = blockIdx.x & 63;
  const int tr = tb >> 3, tc = tb & 7;
  const float* W = (m == 0) ? Wq : (m == 1) ? Wp : Wf;
  bf16*        O = (m == 0) ? WqT : (m == 1) ? WpT : WfT;
  const int r = tid >> 2, cg = tid & 3;
  {
    const float* src = W + (size_t)(tr * 64 + r) * 512 + tc * 64 + cg * 16;
    f32x4 a = *(const f32x4*)src, b2 = *(const f32x4*)(src + 4);
    f32x4 c = *(const f32x4*)(src + 8), d = *(const f32x4*)(src + 12);
    bf16x8 lo, hi;
#pragma unroll
    for (int j = 0; j < 4; j++) { lo[j] = (bf16)a[j]; lo[4 + j] = (bf16)b2[j]; hi[j] = (bf16)c[j]; hi[4 + j] = (bf16)d[j]; }
    *(bf16x8*)(&t[r][cg * 16])     = lo;
    *(bf16x8*)(&t[r][cg * 16 + 8]) = hi;
  }
  __syncthreads();
  bf16x8 o0, o1;
#pragma unroll
  for (int j = 0; j < 8; j++) { o0[j] = t[cg * 16 + j][r]; o1[j] = t[cg * 16 + 8 + j][r]; }
  bf16* dst = O + (size_t)(tc * 64 + r) * 512 + tr * 64 + cg * 16;
  *(bf16x8*)dst = o0;
  *(bf16x8*)(dst + 8) = o1;
}

// ------------- fused projection GEMM, 128x128 tile BK=64, BOTH operands bf16 in LDS
// (X converted fp32->bf16 during staging). LDS 36.9KB -> 4 blocks/CU (16 waves/CU).
__global__ __launch_bounds__(256, 4) void proj_gemm(
    const float* __restrict__ q, const float* __restrict__ k, const float* __restrict__ v,
    const float* __restrict__ pos,
    const bf16* __restrict__ WqT, const bf16* __restrict__ WpT, const float* __restrict__ bq,
    bf16* __restrict__ qh, bf16* __restrict__ kh, bf16* __restrict__ vT, bf16* __restrict__ phx)
{
  __shared__ bf16 As[128 * 72];     // X tile [rr][k=64] bf16, pad 72
  __shared__ bf16 Bs[128 * 72];     // W^T tile [nn][k=64] bf16, pad 72
  const int tid = threadIdx.x;
  const int wave = tid >> 6, lane = tid & 63, quad = lane >> 4, ln = lane & 15;
  const int tn = blockIdx.x & 3;
  const int tm = blockIdx.x >> 2;
  const int kind = tm >> 5;               // 0=q 1=k 2=v 3=pos
  const int rr0 = (tm & 31) * 128;
  const float* X = (kind == 0) ? q : (kind == 1) ? k : (kind == 2) ? v : pos;
  const bf16* WT = ((kind < 3) ? WqT : WpT) + (size_t)tn * 128 * 512;
  const int qn_ = (wave & 1) * 64;        // nn quadrant
  const int qr_ = (wave >> 1) * 64;       // rr quadrant
  const int srow = tid >> 1, shalf = tid & 1;   // staging: 2 thr/row, 32 elems each

  f32x4 acc[4][4] = {};   // [i: nn-sub][j: rr-sub]

  for (int kk = 0; kk < 8; kk++) {
    const int k0 = kk * 64;
    {
      const float* p0 = X + (size_t)(rr0 + srow) * 512 + k0 + shalf * 32;
#pragma unroll
      for (int u = 0; u < 2; u++) {
        f32x4 lo = *(const f32x4*)(p0 + u * 16);
        f32x4 l2 = *(const f32x4*)(p0 + u * 16 + 4);
        f32x4 hi = *(const f32x4*)(p0 + u * 16 + 8);
        f32x4 h2 = *(const f32x4*)(p0 + u * 16 + 12);
        bf16x8 t0, t1;
#pragma unroll
        for (int j = 0; j < 4; j++) { t0[j] = (bf16)lo[j]; t0[4 + j] = (bf16)l2[j]; t1[j] = (bf16)hi[j]; t1[4 + j] = (bf16)h2[j]; }
        *(bf16x8*)(As + srow * 72 + shalf * 32 + u * 16)     = t0;
        *(bf16x8*)(As + srow * 72 + shalf * 32 + u * 16 + 8) = t1;
      }
      const bf16* w0 = WT + (size_t)srow * 512 + k0 + shalf * 32;
#pragma unroll
      for (int u = 0; u < 4; u++)
        *(bf16x8*)(Bs + srow * 72 + shalf * 32 + u * 8) = *(const bf16x8*)(w0 + u * 8);
    }
    __syncthreads();
#pragma unroll
    for (int ks = 0; ks < 2; ks++) {
      bf16x8 xf[4];
#pragma unroll
      for (int j = 0; j < 4; j++)
        xf[j] = *(const bf16x8*)(As + (qr_ + j * 16 + ln) * 72 + ks * 32 + quad * 8);
#pragma unroll
      for (int i = 0; i < 4; i++) {
        bf16x8 wf = *(const bf16x8*)(Bs + (qn_ + i * 16 + ln) * 72 + ks * 32 + quad * 8);
#pragma unroll
        for (int j = 0; j < 4; j++)
          acc[i][j] = __builtin_amdgcn_mfma_f32_16x16x32_bf16(wf, xf[j], acc[i][j], 0, 0, 0);
      }
    }
    __syncthreads();
  }

  // epilogue: lane reg r -> nn = tn*128+qn_+16i+4quad+r (4-run), rr = rr0+qr_+16j+ln
#pragma unroll
  for (int i = 0; i < 4; i++) {
    const int nn0 = tn * 128 + qn_ + i * 16 + quad * 4;
    const int dd0 = nn0 & 31, hh = nn0 >> 5;
    f32x4 b4 = {0.f, 0.f, 0.f, 0.f};
    if (kind < 3) b4 = *(const f32x4*)(bq + nn0);
#pragma unroll
    for (int j = 0; j < 4; j++) {
      const int rr = rr0 + qr_ + j * 16 + ln;
      const int bb = rr >> 10, tt = rr & 1023;
      const size_t base = (size_t)(bb * 16 + hh);
      bf16x4 pk;
#pragma unroll
      for (int r = 0; r < 4; r++) pk[r] = (bf16)(acc[i][j][r] + b4[r]);
      if (kind == 0)      *(bf16x4*)(qh + (base * 1024 + tt) * 32 + dd0) = pk;
      else if (kind == 1) *(bf16x4*)(kh + (base * 1024 + tt) * 32 + dd0) = pk;
      else if (kind == 2) {
#pragma unroll
        for (int r = 0; r < 4; r++) vT[(base * 32 + dd0 + r) * 1024 + tt] = pk[r];
      } else {
        *(bf16x4*)(phx + (base * 2048 + tt) * 32 + dd0) = pk;
        if (tt <= 1021) *(bf16x4*)(phx + (base * 2048 + tt + 1025) * 32 + dd0) = pk;
        if (tt == 1023) {   // fused zero rows 1024 & 2047
          bf16x4 zz = {};
          *(bf16x4*)(phx + (base * 2048 + 1024) * 32 + dd0) = zz;
          *(bf16x4*)(phx + (base * 2048 + 2047) * 32 + dd0) = zz;
        }
      }
    }
  }
}

// ------------- fused flash attention (r8 version: transposed dataflow, barrier-free,
// log2-domain static softmax — no cross-lane ops in the loop)
__global__ __launch_bounds__(256, 4) void attn_kernel(
    const bf16* __restrict__ qh, const bf16* __restrict__ kh,
    const bf16* __restrict__ vT, const bf16* __restrict__ phx,
    const float* __restrict__ u_bias, const float* __restrict__ v_bias,
    bf16* __restrict__ ctx)
{
  __shared__ float fs[4 * 16 * 84];   // per-wave F band [t=16][j=80 pad 84] 21,504 B
  __shared__ bf16  pb[4 * 16 * 72];   // per-wave P [t=16][s=64 pad 72]       9,216 B

  const int tid = threadIdx.x;
  const int wave = tid >> 6, lane = tid & 63, quad = lane >> 4, ln = lane & 15;
  const int wg = blockIdx.x;
  const int bh = wg & 63, tq = wg >> 6;     // XCD-friendly: same head -> same wg%8
  const int h = bh & 15, b = bh >> 4;
  const int t0 = tq * 64;
  const bf16* qh_h  = qh  + (size_t)bh * 1024 * 32;
  const bf16* kh_h  = kh  + (size_t)bh * 1024 * 32;
  const bf16* vT_h  = vT  + (size_t)bh * 32 * 1024;
  const bf16* phx_h = phx + (size_t)bh * 2048 * 32;

  float* fsw = fs + wave * 16 * 84;
  bf16*  pbw = pb + wave * 16 * 72;

  bf16x8 qu, qva, qvn;
  {
    const int t = t0 + wave * 16 + ln;
    bf16x8 q0 = *(const bf16x8*)(qh_h + (size_t)t * 32 + quad * 8);
    bf16x8 q1 = *(const bf16x8*)(qh_h + (size_t)(t + 1) * 32 + quad * 8);  // t=1023 tail: never used
    const float* ubp = u_bias + h * 32 + quad * 8;
    const float* vbp = v_bias + h * 32 + quad * 8;
#pragma unroll
    for (int j = 0; j < 8; j++) {
      qu[j]  = (bf16)(((float)q0[j] + ubp[j]) * SCALE_LOG2);
      qva[j] = (bf16)(((float)q0[j] + vbp[j]) * SCALE_LOG2);
      qvn[j] = (bf16)(((float)q1[j] + vbp[j]) * SCALE_LOG2);
    }
  }

  f32x4 O0 = {0.f, 0.f, 0.f, 0.f}, O1 = {0.f, 0.f, 0.f, 0.f};
  float l_lane = 0.0f;
  const f32x4 zf = {0.f, 0.f, 0.f, 0.f};

#pragma unroll 2
  for (int si = 0; si < 16; si++) {
    const int s0 = si * 64;
    const int jb0 = s0 - t0 + 960 + (3 - wave) * 16;   // 16-aligned

    // ---- F band: 5 subtiles
#pragma unroll
    for (int i = 0; i < 5; i++) {
      bf16x8 pbf = *(const bf16x8*)(phx_h + (size_t)(jb0 + i * 16 + ln) * 32 + quad * 8);
      bf16x8 bsel = (jb0 + i * 16 >= 1024) ? qvn : qva;
      f32x4 f = __builtin_amdgcn_mfma_f32_16x16x32_bf16(pbf, bsel, zf, 0, 0, 0);
      *(f32x4*)(fsw + ln * 84 + i * 16 + quad * 4) = f;
    }

    // ---- content: S^T
    f32x4 c[4];
#pragma unroll
    for (int cs = 0; cs < 4; cs++) {
      bf16x8 kbf = *(const bf16x8*)(kh_h + (size_t)(s0 + cs * 16 + ln) * 32 + quad * 8);
      c[cs] = __builtin_amdgcn_mfma_f32_16x16x32_bf16(kbf, qu, zf, 0, 0, 0);
    }

    // ---- combine + exp2 + accumulate l + stage P
#pragma unroll
    for (int cs = 0; cs < 4; cs++) {
      bf16x4 pk;
#pragma unroll
      for (int r = 0; r < 4; r++) {
        const int col = cs * 16 + quad * 4 + r - ln + 15;   // [0,78]
        const float p = exp2f(c[cs][r] + fsw[ln * 84 + col]);
        l_lane += p;
        pk[r] = (bf16)p;
      }
      *(bf16x4*)(pbw + ln * 72 + cs * 16 + quad * 4) = pk;
    }

    // ---- PV
#pragma unroll
    for (int kb = 0; kb < 2; kb++) {
      bf16x8 a  = *(const bf16x8*)(pbw + ln * 72 + kb * 32 + quad * 8);
      bf16x8 b0 = *(const bf16x8*)(vT_h + (size_t)ln * 1024 + s0 + kb * 32 + quad * 8);
      bf16x8 b1 = *(const bf16x8*)(vT_h + (size_t)(16 + ln) * 1024 + s0 + kb * 32 + quad * 8);
      O0 = __builtin_amdgcn_mfma_f32_16x16x32_bf16(a, b0, O0, 0, 0, 0);
      O1 = __builtin_amdgcn_mfma_f32_16x16x32_bf16(a, b1, O1, 0, 0, 0);
    }
  }

  l_lane += __shfl_xor(l_lane, 16);
  l_lane += __shfl_xor(l_lane, 32);
#pragma unroll
  for (int r = 0; r < 4; r++) {
    const float lr = __shfl(l_lane, quad * 4 + r);
    const float inv = 1.0f / lr;
    const int t = t0 + wave * 16 + quad * 4 + r;
    const size_t o = ((size_t)(b * 1024 + t)) * 512 + h * 32;
    ctx[o + ln]      = (bf16)(O0[r] * inv);
    ctx[o + 16 + ln] = (bf16)(O1[r] * inv);
  }
}

// ------------- output projection: ctx @ Wf + bf -> out (fp32). 64x128 tiles, 256 blocks.
__global__ __launch_bounds__(256) void out_gemm(
    const bf16* __restrict__ ctx, const bf16* __restrict__ WfT, const float* __restrict__ bfv,
    float* __restrict__ out)
{
  __shared__ bf16 As[64 * 40];
  __shared__ bf16 Bs[128 * 40];
  const int tid = threadIdx.x;
  const int wave = tid >> 6, lane = tid & 63, quad = lane >> 4, ln = lane & 15;
  const int tn = blockIdx.x & 3;
  const int tm = blockIdx.x >> 2;       // 0..63
  const int rr0 = tm * 64;
  const bf16* WT = WfT + (size_t)tn * 128 * 512;
  const int qm = (wave & 1) * 32, qn = (wave >> 1) * 64;
  const int srow = tid >> 2, scg = tid & 3;

  f32x4 acc[2][4] = {};
  for (int kk = 0; kk < 16; kk++) {
    const int k0 = kk * 32;
    *(bf16x8*)(As + srow * 40 + scg * 8)        = *(const bf16x8*)(ctx + (size_t)(rr0 + srow) * 512 + k0 + scg * 8);
    *(bf16x8*)(Bs + srow * 40 + scg * 8)        = *(const bf16x8*)(WT + (size_t)srow * 512 + k0 + scg * 8);
    *(bf16x8*)(Bs + (srow + 64) * 40 + scg * 8) = *(const bf16x8*)(WT + (size_t)(srow + 64) * 512 + k0 + scg * 8);
    __syncthreads();
    bf16x8 af[2], bfm[4];
#pragma unroll
    for (int i = 0; i < 2; i++)
      af[i] = *(const bf16x8*)(As + (qm + i * 16 + ln) * 40 + quad * 8);
#pragma unroll
    for (int j = 0; j < 4; j++)
      bfm[j] = *(const bf16x8*)(Bs + (qn + j * 16 + ln) * 40 + quad * 8);
#pragma unroll
    for (int i = 0; i < 2; i++)
#pragma unroll
      for (int j = 0; j < 4; j++)
        acc[i][j] = __builtin_amdgcn_mfma_f32_16x16x32_bf16(af[i], bfm[j], acc[i][j], 0, 0, 0);
    __syncthreads();
  }

#pragma unroll
  for (int i = 0; i < 2; i++)
#pragma unroll
    for (int j = 0; j < 4; j++) {
      const int nn = tn * 128 + qn + j * 16 + ln;
      const float bias = bfv[nn];
#pragma unroll
      for (int r = 0; r < 4; r++) {
        const int rr = rr0 + qm + i * 16 + quad * 4 + r;
        out[(size_t)rr * 512 + nn] = acc[i][j][r] + bias;
      }
    }
}

// ---------------------------------------------------------------------------
extern "C" void kernel_launch(void* const* d_in, const int* in_sizes, int n_in,
                              void* d_out, int out_size, void* d_ws, size_t ws_size,
                              hipStream_t stream) {
  const float* q   = (const float*)d_in[0];
  const float* k   = (const float*)d_in[1];
  const float* v   = (const float*)d_in[2];
  const float* pe  = (const float*)d_in[3];
  const float* Wq  = (const float*)d_in[4];
  const float* bq  = (const float*)d_in[5];
  const float* Wp  = (const float*)d_in[6];
  const float* Wf  = (const float*)d_in[7];
  const float* bfv = (const float*)d_in[8];
  const float* ub  = (const float*)d_in[9];
  const float* vb  = (const float*)d_in[10];

  bf16* ws  = (bf16*)d_ws;
  bf16* qh  = ws;                  // qh first: t+1 tail reads land in kh (finite, unused)
  bf16* kh  = qh + 2097152;
  bf16* vT  = kh + 2097152;
  bf16* phx = vT + 2097152;
  bf16* ctx = phx + 4194304;
  bf16* WqT = ctx + 2097152;
  bf16* WpT = WqT + 262144;
  bf16* WfT = WpT + 262144;

  prep_kernel<<<192, 256, 0, stream>>>(Wq, Wp, Wf, WqT, WpT, WfT);
  proj_gemm<<<512, 256, 0, stream>>>(q, k, v, pe, WqT, WpT, bq, qh, kh, vT, phx);
  attn_kernel<<<1024, 256, 0, stream>>>(qh, kh, vT, phx, ub, vb, ctx);
  out_gemm<<<256, 256, 0, stream>>>(ctx, WfT, bfv, (float*)d_out);
}